// Round 8
// baseline (1091.951 us; speedup 1.0000x reference)
//
#include <hip/hip_runtime.h>

#define BATCH 8
#define NPTS 4096
#define NSAMP 512   // npoint = NPTS/8

#define ROW_SHR(n) (0x110 | (n))
#define ROW_BCAST15 0x142
#define ROW_BCAST31 0x143

// one max-combine step on a packed u64 key via DPP (VALU latency, no LDS).
template <int CTRL, int RMASK>
__device__ __forceinline__ unsigned long long kmax_dpp(unsigned long long k) {
  unsigned lo = (unsigned)__builtin_amdgcn_update_dpp(0, (int)(unsigned)k,
                                                      CTRL, RMASK, 0xf, true);
  unsigned hi = (unsigned)__builtin_amdgcn_update_dpp(0, (int)(unsigned)(k >> 32),
                                                      CTRL, RMASK, 0xf, true);
  unsigned long long o = ((unsigned long long)hi << 32) | lo;
  return o > k ? o : k;   // masked/OOB lanes deliver 0 -> identity
}

// ---------------------------------------------------------------------------
// Kernel A: farthest point sampling (r3 version — best measured ~250 us).
// Exact fp32 (no FMA contraction) so argmax selection matches numpy exactly.
// key = (float_bits(val) << 32) | ~idx  => u64-max == (max, tie->smaller idx).
// ---------------------------------------------------------------------------
__global__ __launch_bounds__(256) void fps_kernel(const float* __restrict__ pcd,
                                                  float* __restrict__ new_xyz) {
  __shared__ float4 s_pts[NPTS];                       // 64 KB
  __shared__ unsigned long long red[2][4];             // parity double-buffer

  const int b = blockIdx.x;
  const int t = threadIdx.x;
  const int wave = t >> 6;
  const int lane = t & 63;
  const float* xb = pcd + (size_t)b * NPTS * 3;

  float X[16], Y[16], Z[16], mind[16];
#pragma unroll
  for (int j = 0; j < 16; ++j) {
    int i = t + 256 * j;
    float x = xb[i * 3 + 0], y = xb[i * 3 + 1], z = xb[i * 3 + 2];
    X[j] = x; Y[j] = y; Z[j] = z;
    s_pts[i] = make_float4(x, y, z, 0.0f);
    mind[j] = 10000000000.0f;
  }
  __syncthreads();

  float px = xb[0], py = xb[1], pz = xb[2];            // idx 0 is first sample

  for (int it = 0; it < NSAMP; ++it) {
    if (t == 0) {
      size_t o = ((size_t)b * NSAMP + it) * 3;
      new_xyz[o + 0] = px; new_xyz[o + 1] = py; new_xyz[o + 2] = pz;
    }
    float bv = -1.0f; int bi = 0;
#pragma unroll
    for (int j = 0; j < 16; ++j) {
      float dx = __fsub_rn(X[j], px);
      float dy = __fsub_rn(Y[j], py);
      float dz = __fsub_rn(Z[j], pz);
      float d = __fadd_rn(__fadd_rn(__fmul_rn(dx, dx), __fmul_rn(dy, dy)),
                          __fmul_rn(dz, dz));
      float m = fminf(mind[j], d);
      mind[j] = m;
      if (m > bv) { bv = m; bi = t + 256 * j; }        // strict >: first occ.
    }
    unsigned long long key =
        ((unsigned long long)__float_as_uint(bv) << 32) |
        (unsigned long long)(~(unsigned)bi);
    key = kmax_dpp<ROW_SHR(1), 0xf>(key);
    key = kmax_dpp<ROW_SHR(2), 0xf>(key);
    key = kmax_dpp<ROW_SHR(4), 0xf>(key);
    key = kmax_dpp<ROW_SHR(8), 0xf>(key);
    key = kmax_dpp<ROW_BCAST15, 0xa>(key);
    key = kmax_dpp<ROW_BCAST31, 0xc>(key);
    unsigned wlo = (unsigned)__builtin_amdgcn_readlane((int)(unsigned)key, 63);
    unsigned whi = (unsigned)__builtin_amdgcn_readlane((int)(unsigned)(key >> 32), 63);
    if (lane == 0)
      red[it & 1][wave] = ((unsigned long long)whi << 32) | wlo;
    __syncthreads();
    unsigned long long g = red[it & 1][0];
    unsigned long long g1 = red[it & 1][1];
    unsigned long long g2 = red[it & 1][2];
    unsigned long long g3 = red[it & 1][3];
    if (g1 > g) g = g1;
    if (g2 > g) g = g2;
    if (g3 > g) g = g3;
    int nxt = (int)(~(unsigned)g);
    float4 p = s_pts[nxt];
    px = p.x; py = p.y; pz = p.z;
  }
}

// ---------------------------------------------------------------------------
// Weight prep: transpose each w[cin][cout] into wt[cout][cinp] (cin padded
// to a multiple of 4 with zeros) so MLP threads can float4-load weights.
// ---------------------------------------------------------------------------
__device__ __forceinline__ void tsec(int g, const float* __restrict__ w,
                                     float* __restrict__ wt, int cin, int cinp,
                                     int cout, int base) {
  int local = g - base;
  if (local < 0 || local >= cinp * cout) return;
  int oc = local / cinp, ic = local % cinp;
  wt[base + local] = (ic < cin) ? w[ic * cout + oc] : 0.0f;
}

#define W00 0
#define W01 128
#define W02 1152
#define W10 3200
#define W11 3456
#define W12 7552
#define W20 15744
#define W21 16000
#define W22 22144
#define WT_TOTAL 34432

__global__ __launch_bounds__(256) void prep_kernel(
    const float* w00, const float* w01, const float* w02,
    const float* w10, const float* w11, const float* w12,
    const float* w20, const float* w21, const float* w22,
    float* __restrict__ wt) {
  int g = blockIdx.x * 256 + threadIdx.x;
  tsec(g, w00, wt, 3, 4, 32, W00);
  tsec(g, w01, wt, 32, 32, 32, W01);
  tsec(g, w02, wt, 32, 32, 64, W02);
  tsec(g, w10, wt, 3, 4, 64, W10);
  tsec(g, w11, wt, 64, 64, 64, W11);
  tsec(g, w12, wt, 64, 64, 128, W12);
  tsec(g, w20, wt, 3, 4, 64, W20);
  tsec(g, w21, wt, 64, 64, 96, W21);
  tsec(g, w22, wt, 96, 96, 128, W22);
}

// ---------------------------------------------------------------------------
// Wave-level MLP building blocks. Lane layout: og = lane>>3 (8 output
// groups), nl = lane&7 (8 n-lanes, TN=2 -> 16 neighbors per tile).
// h buffers are wave-private LDS, row stride 16 floats. Input-channel
// accumulation order is sequential 0..CIN-1 => bitwise identical to ref.
// ---------------------------------------------------------------------------
template <int TOC>
__device__ __forceinline__ void ib(float (&acc)[TOC][2], const float* bias) {
#pragma unroll
  for (int j = 0; j < TOC; ++j) { float bj = bias[j]; acc[j][0] = bj; acc[j][1] = bj; }
}

// first layer: K=3 from a staging buffer (x,y,z rows, col stride CST)
template <int TOC, int CST>
__device__ __forceinline__ void l0(const float* __restrict__ wtb,
                                   const float* cb, int nb, int nl,
                                   float (&acc)[TOC][2]) {
  float2 hx = *(const float2*)&cb[0 * CST + nb + nl * 2];
  float2 hy = *(const float2*)&cb[1 * CST + nb + nl * 2];
  float2 hz = *(const float2*)&cb[2 * CST + nb + nl * 2];
#pragma unroll
  for (int j = 0; j < TOC; ++j) {
    float4 w = *(const float4*)&wtb[j * 4];
    acc[j][0] = fmaf(hx.x, w.x, acc[j][0]); acc[j][1] = fmaf(hx.y, w.x, acc[j][1]);
    acc[j][0] = fmaf(hy.x, w.y, acc[j][0]); acc[j][1] = fmaf(hy.y, w.y, acc[j][1]);
    acc[j][0] = fmaf(hz.x, w.z, acc[j][0]); acc[j][1] = fmaf(hz.y, w.z, acc[j][1]);
  }
}

// inner layer: KC4*4 input channels from h (row stride 16), weight row
// stride WS; accumulates into acc (persists across split-K calls).
template <int TOC, int KC4, int WS>
__device__ __forceinline__ void lk(const float* __restrict__ wtb,
                                   const float* hin, int nl,
                                   float (&acc)[TOC][2]) {
#pragma unroll 2
  for (int c4 = 0; c4 < KC4; ++c4) {
    float2 hv[4];
#pragma unroll
    for (int k = 0; k < 4; ++k)
      hv[k] = *(const float2*)&hin[(c4 * 4 + k) * 16 + nl * 2];
#pragma unroll
    for (int j = 0; j < TOC; ++j) {
      float4 w = *(const float4*)&wtb[j * WS + c4 * 4];
      acc[j][0] = fmaf(hv[0].x, w.x, acc[j][0]); acc[j][1] = fmaf(hv[0].y, w.x, acc[j][1]);
      acc[j][0] = fmaf(hv[1].x, w.y, acc[j][0]); acc[j][1] = fmaf(hv[1].y, w.y, acc[j][1]);
      acc[j][0] = fmaf(hv[2].x, w.z, acc[j][0]); acc[j][1] = fmaf(hv[2].y, w.z, acc[j][1]);
      acc[j][0] = fmaf(hv[3].x, w.w, acc[j][0]); acc[j][1] = fmaf(hv[3].y, w.w, acc[j][1]);
    }
  }
}

template <int TOC>
__device__ __forceinline__ void st(float* hbuf, int rowbase, int nl,
                                   float (&acc)[TOC][2]) {
#pragma unroll
  for (int j = 0; j < TOC; ++j)
    *(float2*)&hbuf[(rowbase + j) * 16 + nl * 2] =
        make_float2(fmaxf(acc[j][0], 0.0f), fmaxf(acc[j][1], 0.0f));
}

template <int TOC>
__device__ __forceinline__ void rupd(float (&r)[TOC], float (&acc)[TOC][2]) {
#pragma unroll
  for (int j = 0; j < TOC; ++j)
    r[j] = fmaxf(r[j], fmaxf(acc[j][0], acc[j][1]));
}

// cross-lane max over the 8 n-lanes, then partial dot with wf (nl==0 lanes)
template <int TOC>
__device__ __forceinline__ float rdot(float (&r)[TOC], const float* wfp, int nl) {
  float s = 0.0f;
#pragma unroll
  for (int j = 0; j < TOC; ++j) {
    float v = r[j];
    v = fmaxf(v, __shfl_xor(v, 1));
    v = fmaxf(v, __shfl_xor(v, 2));
    v = fmaxf(v, __shfl_xor(v, 4));
    if (nl == 0) s = fmaf(v, wfp[j], s);
  }
  return s;
}

// ---------------------------------------------------------------------------
// Kernel B: wave-autonomous. One WAVE per sample point; 4 samples per block;
// zero __syncthreads. Per-wave LDS slice (2320 floats = 9280 B):
//   c2[3][128] | c1[3][32] | c0[3][16] | h1[64][16] | h2[48][16]
// Ball query: 64 ballot rounds writing centered coords at prefix positions.
// MLPs: h1/h2 ping-pong; layers with >48 output rows run as two sequential
// halves with the next layer's accumulators persisting in registers.
// ---------------------------------------------------------------------------
#define LDSW 2320

__global__ __launch_bounds__(256) void msg_kernel(
    const float* __restrict__ pcd, const float* __restrict__ new_xyz,
    const float* __restrict__ wt,
    const float* __restrict__ b00, const float* __restrict__ b01,
    const float* __restrict__ b02, const float* __restrict__ b10,
    const float* __restrict__ b11, const float* __restrict__ b12,
    const float* __restrict__ b20, const float* __restrict__ b21,
    const float* __restrict__ b22,
    const float* __restrict__ wf, const float* __restrict__ bf,
    float* __restrict__ out) {
  __shared__ float lds[4 * LDSW];      // 37120 B -> 4 blocks/CU

  const int tid = threadIdx.x;
  const int wave = tid >> 6;
  const int lane = tid & 63;
  const int og = lane >> 3;
  const int nl = lane & 7;
  const int bs = blockIdx.x * 4 + wave;
  const int b = bs >> 9;
  const float* xb = pcd + (size_t)b * NPTS * 3;

  float* Wl = lds + wave * LDSW;
  float* c2 = Wl;              // [3][128]
  float* c1 = Wl + 384;        // [3][32]
  float* c0 = Wl + 480;        // [3][16]
  float* h1 = Wl + 528;        // [64][16]
  float* h2 = Wl + 1552;       // [48][16]

  const float cxv = new_xyz[(size_t)bs * 3 + 0];
  const float cyv = new_xyz[(size_t)bs * 3 + 1];
  const float czv = new_xyz[(size_t)bs * 3 + 2];

  // ---- ball query: 64 rounds, 3 ballots each, direct staged writes ----
  const float r2a = (float)(0.1 * 0.1);
  const float r2b = (float)(0.2 * 0.2);
  const float r2c = (float)(0.4 * 0.4);
  const unsigned long long below = (lane == 63) ? ~0ull >> 1
                                                : (1ull << lane) - 1ull;
  int cnt0 = 0, cnt1 = 0, cnt2 = 0;
  for (int ch = 0; ch < 64; ++ch) {
    const float* p = xb + (size_t)((ch << 6) | lane) * 3;
    float dx = __fsub_rn(p[0], cxv);
    float dy = __fsub_rn(p[1], cyv);
    float dz = __fsub_rn(p[2], czv);
    float sq = __fadd_rn(__fadd_rn(__fmul_rn(dx, dx), __fmul_rn(dy, dy)),
                         __fmul_rn(dz, dz));
    bool i0 = sq < r2a, i1 = sq < r2b, i2 = sq < r2c;
    unsigned long long m0 = __ballot(i0);
    unsigned long long m1 = __ballot(i1);
    unsigned long long m2 = __ballot(i2);
    if (i0) {
      int pos = cnt0 + (int)__popcll(m0 & below);
      if (pos < 16) { c0[pos] = dx; c0[16 + pos] = dy; c0[32 + pos] = dz; }
    }
    if (i1) {
      int pos = cnt1 + (int)__popcll(m1 & below);
      if (pos < 32) { c1[pos] = dx; c1[32 + pos] = dy; c1[64 + pos] = dz; }
    }
    if (i2) {
      int pos = cnt2 + (int)__popcll(m2 & below);
      if (pos < 128) { c2[pos] = dx; c2[128 + pos] = dy; c2[256 + pos] = dz; }
    }
    cnt0 += (int)__popcll(m0);
    cnt1 += (int)__popcll(m1);
    cnt2 += (int)__popcll(m2);
  }
  // pads: replicate the first (lowest-index) in-radius point
  if (cnt0 < 16) {
    float fx = c0[0], fy = c0[16], fz = c0[32];
    int k = cnt0 + lane;
    if (k < 16) { c0[k] = fx; c0[16 + k] = fy; c0[32 + k] = fz; }
  }
  if (cnt1 < 32) {
    float fx = c1[0], fy = c1[32], fz = c1[64];
    int k = cnt1 + lane;
    if (k < 32) { c1[k] = fx; c1[32 + k] = fy; c1[64 + k] = fz; }
  }
  if (cnt2 < 128) {
    float fx = c2[0], fy = c2[128], fz = c2[256];
    for (int k = cnt2 + lane; k < 128; k += 64) {
      c2[k] = fx; c2[128 + k] = fy; c2[256 + k] = fz;
    }
  }

  float dot = 0.0f;

  // ---- scale 0: ns=16 (1 tile), 3->32->32->64 ----
  {
    float a0[4][2]; ib<4>(a0, b00 + og * 4);
    l0<4, 16>(wt + W00 + (og * 4) * 4, c0, 0, nl, a0);
    st<4>(h1, og * 4, nl, a0);
    float a1[4][2]; ib<4>(a1, b01 + og * 4);
    lk<4, 8, 32>(wt + W01 + (og * 4) * 32, h1, nl, a1);
    st<4>(h2, og * 4, nl, a1);
    float a2[8][2]; ib<8>(a2, b02 + og * 8);
    lk<8, 8, 32>(wt + W02 + (og * 8) * 32, h2, nl, a2);
    float r0[8];
#pragma unroll
    for (int j = 0; j < 8; ++j) r0[j] = fmaxf(0.0f, fmaxf(a2[j][0], a2[j][1]));
    dot += rdot<8>(r0, wf + og * 8, nl);
  }

  // ---- scale 1: ns=32 (2 tiles of 16), 3->64->64->128 ----
  {
    float r1[16];
#pragma unroll
    for (int j = 0; j < 16; ++j) r1[j] = 0.0f;
#pragma unroll
    for (int nt = 0; nt < 2; ++nt) {
      float a0[8][2]; ib<8>(a0, b10 + og * 8);
      l0<8, 32>(wt + W10 + (og * 8) * 4, c1, nt * 16, nl, a0);
      st<8>(h1, og * 8, nl, a0);
      float a2[16][2]; ib<16>(a2, b12 + og * 16);
#pragma unroll
      for (int h = 0; h < 2; ++h) {
        float a1[4][2]; ib<4>(a1, b11 + h * 32 + og * 4);
        lk<4, 16, 64>(wt + W11 + (h * 32 + og * 4) * 64, h1, nl, a1);
        st<4>(h2, og * 4, nl, a1);
        lk<16, 8, 64>(wt + W12 + (og * 16) * 64 + h * 32, h2, nl, a2);
      }
      rupd<16>(r1, a2);
    }
    dot += rdot<16>(r1, wf + 64 + og * 16, nl);
  }

  // ---- scale 2: ns=128 (8 tiles of 16), 3->64->96->128 ----
  {
    float r2[16];
#pragma unroll
    for (int j = 0; j < 16; ++j) r2[j] = 0.0f;
    for (int nt = 0; nt < 8; ++nt) {
      float a0[8][2]; ib<8>(a0, b20 + og * 8);
      l0<8, 128>(wt + W20 + (og * 8) * 4, c2, nt * 16, nl, a0);
      st<8>(h1, og * 8, nl, a0);
      float a2[16][2]; ib<16>(a2, b22 + og * 16);
#pragma unroll
      for (int h = 0; h < 2; ++h) {
        float a1[6][2]; ib<6>(a1, b21 + h * 48 + og * 6);
        lk<6, 16, 64>(wt + W21 + (h * 48 + og * 6) * 64, h1, nl, a1);
        st<6>(h2, og * 6, nl, a1);
        lk<16, 12, 96>(wt + W22 + (og * 16) * 96 + h * 48, h2, nl, a2);
      }
      rupd<16>(r2, a2);
    }
    dot += rdot<16>(r2, wf + 192 + og * 16, nl);
  }

  // ---- wave-sum of partial dots, write output ----
#pragma unroll
  for (int o = 1; o < 64; o <<= 1) dot += __shfl_xor(dot, o);
  if (lane == 0) out[bs] = dot + bf[0];
}

extern "C" void kernel_launch(void* const* d_in, const int* in_sizes, int n_in,
                              void* d_out, int out_size, void* d_ws, size_t ws_size,
                              hipStream_t stream) {
  const float* pcd = (const float*)d_in[0];
  float* wsf = (float*)d_ws;
  float* new_xyz = wsf;                 // 8*512*3 = 12288 floats (48 KB)
  float* wt = wsf + 12288;              // 34432 floats (transposed weights)

  prep_kernel<<<(WT_TOTAL + 255) / 256, 256, 0, stream>>>(
      (const float*)d_in[1], (const float*)d_in[3], (const float*)d_in[5],
      (const float*)d_in[7], (const float*)d_in[9], (const float*)d_in[11],
      (const float*)d_in[13], (const float*)d_in[15], (const float*)d_in[17],
      wt);

  fps_kernel<<<BATCH, 256, 0, stream>>>(pcd, new_xyz);

  msg_kernel<<<BATCH * NSAMP / 4, 256, 0, stream>>>(
      pcd, new_xyz, wt,
      (const float*)d_in[2],  (const float*)d_in[4],  (const float*)d_in[6],
      (const float*)d_in[8],  (const float*)d_in[10], (const float*)d_in[12],
      (const float*)d_in[14], (const float*)d_in[16], (const float*)d_in[18],
      (const float*)d_in[19], (const float*)d_in[20],
      (float*)d_out);
}

// Round 9
// 787.841 us; speedup vs baseline: 1.3860x; 1.3860x over previous
//
#include <hip/hip_runtime.h>

#define BATCH 8
#define NPTS 4096
#define NSAMP 512   // npoint = NPTS/8

#define ROW_SHR(n) (0x110 | (n))
#define ROW_BCAST15 0x142
#define ROW_BCAST31 0x143

// f32 max-combine via DPP. bound_ctrl holes deliver 0.0f — identity here
// because per-thread best distances are always >= 0.
template <int CTRL, int RMASK>
__device__ __forceinline__ float fmax_dpp(float x) {
  int t = __builtin_amdgcn_update_dpp(0, __float_as_int(x), CTRL, RMASK, 0xf, true);
  return fmaxf(x, __int_as_float(t));
}

// ---------------------------------------------------------------------------
// Kernel A: farthest point sampling. One block per batch, 256 threads,
// thread t owns points [16t,16t+16) (contiguous) => lane order == index
// order and wave order == index-range order, so f32-max + ballot/ffs +
// strict-> cross-wave combine reproduces np.argmax first-occurrence exactly.
// Exact fp32 (no FMA contraction) for bit-identical selection values.
// ---------------------------------------------------------------------------
__global__ __launch_bounds__(256) void fps_kernel(const float* __restrict__ pcd,
                                                  float* __restrict__ new_xyz) {
  __shared__ float4 s_pts[NPTS];   // 64 KB coord table for winner gather
  __shared__ float4 slot[2][4];    // per-wave winner (x,y,z,val), parity dbuf

  const int b = blockIdx.x;
  const int t = threadIdx.x;
  const int wave = t >> 6;
  const int lane = t & 63;
  const float* xb = pcd + (size_t)b * NPTS * 3;

  float X[16], Y[16], Z[16], mind[16];
  {
    float f[48];
    float4* vv = (float4*)f;
    const float4* src = (const float4*)xb + t * 12;   // 192 B/thread
#pragma unroll
    for (int q = 0; q < 12; ++q) vv[q] = src[q];
#pragma unroll
    for (int j = 0; j < 16; ++j) {
      X[j] = f[3 * j + 0]; Y[j] = f[3 * j + 1]; Z[j] = f[3 * j + 2];
      mind[j] = 10000000000.0f;
      s_pts[t * 16 + j] = make_float4(X[j], Y[j], Z[j], 0.0f);
    }
  }
  __syncthreads();

  float px = xb[0], py = xb[1], pz = xb[2];   // first sample is index 0

  for (int it = 0; it < NSAMP; ++it) {
    if (t == 0) {
      size_t o = ((size_t)b * NSAMP + it) * 3;
      new_xyz[o + 0] = px; new_xyz[o + 1] = py; new_xyz[o + 2] = pz;
    }
    // ---- update min-dist + local argmax (strict > = first occurrence) ----
    float bv = -1.0f; int bi = 0;
#pragma unroll
    for (int j = 0; j < 16; ++j) {
      float dx = __fsub_rn(X[j], px);
      float dy = __fsub_rn(Y[j], py);
      float dz = __fsub_rn(Z[j], pz);
      float d = __fadd_rn(__fadd_rn(__fmul_rn(dx, dx), __fmul_rn(dy, dy)),
                          __fmul_rn(dz, dz));
      float m = fminf(mind[j], d);
      mind[j] = m;
      bool g = m > bv;
      bv = g ? m : bv;
      bi = g ? t * 16 + j : bi;
    }
    // ---- wave max via f32 DPP; ballot+ffs -> exact lowest-index winner ---
    float m6 = bv;
    m6 = fmax_dpp<ROW_SHR(1), 0xf>(m6);
    m6 = fmax_dpp<ROW_SHR(2), 0xf>(m6);
    m6 = fmax_dpp<ROW_SHR(4), 0xf>(m6);
    m6 = fmax_dpp<ROW_SHR(8), 0xf>(m6);
    m6 = fmax_dpp<ROW_BCAST15, 0xa>(m6);
    m6 = fmax_dpp<ROW_BCAST31, 0xc>(m6);
    float wmax = __int_as_float(
        __builtin_amdgcn_readlane(__float_as_int(m6), 63));
    unsigned long long msk = __ballot(bv == wmax);
    if (lane == __ffsll(msk) - 1) {
      float4 p = s_pts[bi];
      p.w = wmax;
      slot[it & 1][wave] = p;
    }
    __syncthreads();
    // ---- cross-wave combine; strict > keeps lowest wave = lowest index ---
    float4 cur = slot[it & 1][0];
#pragma unroll
    for (int w = 1; w < 4; ++w) {
      float4 sw = slot[it & 1][w];
      if (sw.w > cur.w) cur = sw;
    }
    px = cur.x; py = cur.y; pz = cur.z;
  }
}

// ---------------------------------------------------------------------------
// Weight prep: transpose each w[cin][cout] into wt[cout][cinp] (cin padded
// to a multiple of 4 with zeros) so MLP threads can float4-load weights.
// ---------------------------------------------------------------------------
__device__ __forceinline__ void tsec(int g, const float* __restrict__ w,
                                     float* __restrict__ wt, int cin, int cinp,
                                     int cout, int base) {
  int local = g - base;
  if (local < 0 || local >= cinp * cout) return;
  int oc = local / cinp, ic = local % cinp;
  wt[base + local] = (ic < cin) ? w[ic * cout + oc] : 0.0f;
}

#define W00 0
#define W01 128
#define W02 1152
#define W10 3200
#define W11 3456
#define W12 7552
#define W20 15744
#define W21 16000
#define W22 22144
#define WT_TOTAL 34432

__global__ __launch_bounds__(256) void prep_kernel(
    const float* w00, const float* w01, const float* w02,
    const float* w10, const float* w11, const float* w12,
    const float* w20, const float* w21, const float* w22,
    float* __restrict__ wt) {
  int g = blockIdx.x * 256 + threadIdx.x;
  tsec(g, w00, wt, 3, 4, 32, W00);
  tsec(g, w01, wt, 32, 32, 32, W01);
  tsec(g, w02, wt, 32, 32, 64, W02);
  tsec(g, w10, wt, 3, 4, 64, W10);
  tsec(g, w11, wt, 64, 64, 64, W11);
  tsec(g, w12, wt, 64, 64, 128, W12);
  tsec(g, w20, wt, 3, 4, 64, W20);
  tsec(g, w21, wt, 64, 64, 96, W21);
  tsec(g, w22, wt, 96, 96, 128, W22);
}

// ---------------------------------------------------------------------------
// Kernel B1: ball query. One block per sample. Phase 1: 256 threads build
// in-radius bitmasks (3 radii x 64 chunks). Phase 2: wave s, lane c owns
// chunk c — popcount prefix-scan gives each chunk its output offset, then
// lanes emit their set bits in parallel (global ascending index order ==
// reference sort order). Lists fully padded with the first hit.
// ---------------------------------------------------------------------------
__global__ __launch_bounds__(256) void bq_kernel(
    const float* __restrict__ pcd, const float* __restrict__ new_xyz,
    unsigned short* __restrict__ glists) {
  __shared__ unsigned long long masks[3][64];

  const int bs = blockIdx.x;
  const int b = bs >> 9;
  const int tid = threadIdx.x;
  const int lane = tid & 63;
  const int wave = tid >> 6;
  const float* xb = pcd + (size_t)b * NPTS * 3;

  const float cx = new_xyz[(size_t)bs * 3 + 0];
  const float cy = new_xyz[(size_t)bs * 3 + 1];
  const float cz = new_xyz[(size_t)bs * 3 + 2];

  const float r2a = (float)(0.1 * 0.1);
  const float r2b = (float)(0.2 * 0.2);
  const float r2c = (float)(0.4 * 0.4);
#pragma unroll 4
  for (int j = 0; j < 16; ++j) {
    int i = (j << 8) | tid;
    const float* p = xb + i * 3;
    float dx = __fsub_rn(cx, p[0]);
    float dy = __fsub_rn(cy, p[1]);
    float dz = __fsub_rn(cz, p[2]);
    float sq = __fadd_rn(__fadd_rn(__fmul_rn(dx, dx), __fmul_rn(dy, dy)),
                         __fmul_rn(dz, dz));
    unsigned long long m0 = __ballot(sq < r2a);
    unsigned long long m1 = __ballot(sq < r2b);
    unsigned long long m2 = __ballot(sq < r2c);
    if (lane == 0) {
      int c = (j << 2) | wave;
      masks[0][c] = m0; masks[1][c] = m1; masks[2][c] = m2;
    }
  }
  __syncthreads();

  if (wave < 3) {
    const int ns  = (wave == 0) ? 16 : (wave == 1) ? 32 : 128;
    const int off = (wave == 0) ? 0  : (wave == 1) ? 16 : 48;
    unsigned long long m = masks[wave][lane];
    int pc = (int)__popcll(m);
    int incl = pc;
#pragma unroll
    for (int o = 1; o < 64; o <<= 1) {
      int u = __shfl_up(incl, o);
      if (lane >= o) incl += u;
    }
    int ex = incl - pc;
    int total = __shfl(incl, 63);
    unsigned short* gl = glists + (size_t)bs * 176 + off;
    unsigned long long mm = m;
    int p = ex;
    while (mm && p < ns) {
      int l = (int)__builtin_ctzll(mm);
      mm &= mm - 1;
      gl[p++] = (unsigned short)((lane << 6) | l);
    }
    int cnt = total < ns ? total : ns;
    unsigned long long nz = __ballot(pc > 0);
    int fl = __ffsll(nz) - 1;                   // center guarantees nz != 0
    int myf = (lane << 6) | (int)__builtin_ctzll(m | 0x8000000000000000ull);
    int fidx = __shfl(myf, fl);
    for (int k = cnt + lane; k < ns; k += 64) gl[k] = (unsigned short)fidx;
  }
}

// ---------------------------------------------------------------------------
// MLP building blocks (16 n-threads x 16 oc-threads). Input-channel
// accumulation order is sequential 0..CIN-1 => bitwise identical to ref.
// ---------------------------------------------------------------------------
template <int TOC, int TN>
__device__ __forceinline__ void ib(float (&acc)[TOC][TN], const float* bias) {
#pragma unroll
  for (int j = 0; j < TOC; ++j) {
    float bj = bias[j];
#pragma unroll
    for (int i = 0; i < TN; ++i) acc[j][i] = bj;
  }
}

template <int CIN4, int TOC, int TN, int NTPI, int WS>
__device__ __forceinline__ void layer_acc(const float* __restrict__ wtb,
                                          const float* hin,
                                          float (&acc)[TOC][TN], int tn) {
#pragma unroll 2
  for (int c4 = 0; c4 < CIN4; ++c4) {
    float hv[4][TN];
#pragma unroll
    for (int k = 0; k < 4; ++k) {
      const float* src = &hin[(c4 * 4 + k) * NTPI + tn * TN];
      if constexpr (TN == 1) {
        hv[k][0] = src[0];
      } else if constexpr (TN == 2) {
        float2 v = *(const float2*)src; hv[k][0] = v.x; hv[k][1] = v.y;
      } else {
        float4 v = *(const float4*)src;
        hv[k][0] = v.x; hv[k][1] = v.y; hv[k][2] = v.z; hv[k][3] = v.w;
      }
    }
#pragma unroll
    for (int j = 0; j < TOC; ++j) {
      float4 w4 = *(const float4*)&wtb[j * WS + c4 * 4];
#pragma unroll
      for (int i = 0; i < TN; ++i) {
        acc[j][i] = fmaf(hv[0][i], w4.x, acc[j][i]);
        acc[j][i] = fmaf(hv[1][i], w4.y, acc[j][i]);
        acc[j][i] = fmaf(hv[2][i], w4.z, acc[j][i]);
        acc[j][i] = fmaf(hv[3][i], w4.w, acc[j][i]);
      }
    }
  }
}

template <int TOC, int TN, int NTPO>
__device__ __forceinline__ void store_relu(float* hout,   // + ocrow*NTPO
                                           float (&acc)[TOC][TN], int tn) {
#pragma unroll
  for (int j = 0; j < TOC; ++j) {
    float* dst = &hout[j * NTPO + tn * TN];
    if constexpr (TN == 1) {
      dst[0] = fmaxf(acc[j][0], 0.0f);
    } else if constexpr (TN == 2) {
      *(float2*)dst = make_float2(fmaxf(acc[j][0], 0.0f),
                                  fmaxf(acc[j][1], 0.0f));
    } else {
      *(float4*)dst = make_float4(fmaxf(acc[j][0], 0.0f),
                                  fmaxf(acc[j][1], 0.0f),
                                  fmaxf(acc[j][2], 0.0f),
                                  fmaxf(acc[j][3], 0.0f));
    }
  }
}

template <int TOC, int TN>
__device__ __forceinline__ void rmax_upd(float (&r)[TOC],
                                         float (&acc)[TOC][TN]) {
#pragma unroll
  for (int j = 0; j < TOC; ++j) {
    float m = 0.0f;   // relu floor
#pragma unroll
    for (int i = 0; i < TN; ++i) m = fmaxf(m, acc[j][i]);
    r[j] = fmaxf(r[j], m);
  }
}

// reduce over the 16 threads sharing an oc-row (consecutive lanes) and have
// the tn==0 lane write feat — no atomics, no init.
template <int TOC>
__device__ __forceinline__ void rmax_commit(float* fdst, float (&r)[TOC],
                                            int tn) {
#pragma unroll
  for (int j = 0; j < TOC; ++j) {
    float v = r[j];
    v = fmaxf(v, __shfl_xor(v, 1));
    v = fmaxf(v, __shfl_xor(v, 2));
    v = fmaxf(v, __shfl_xor(v, 4));
    v = fmaxf(v, __shfl_xor(v, 8));
    if (tn == 0) fdst[j] = v;
  }
}

// ---------------------------------------------------------------------------
// Kernel B2: MLPs only. One block per sample. 11 barrier windows, every
// window contains >=1 fat GEMM; staging goes to a separate cbuf so it
// overlaps compute windows. Index lists come pre-padded from bq_kernel.
// ---------------------------------------------------------------------------
__global__ __launch_bounds__(256) void msg_kernel(
    const float* __restrict__ pcd, const float* __restrict__ new_xyz,
    const float* __restrict__ wt, const unsigned short* __restrict__ glists,
    const float* __restrict__ b00, const float* __restrict__ b01,
    const float* __restrict__ b02, const float* __restrict__ b10,
    const float* __restrict__ b11, const float* __restrict__ b12,
    const float* __restrict__ b20, const float* __restrict__ b21,
    const float* __restrict__ b22,
    const float* __restrict__ wf, const float* __restrict__ bf,
    float* __restrict__ out) {
  __shared__ __align__(16) float hA[96 * 68];    // 26112 B
  __shared__ __align__(16) float hB[64 * 68];    // 17408 B
  __shared__ __align__(16) float cbuf[4 * 68];   //  1088 B
  __shared__ float feat[320];                    //  1280 B

  const int bs = blockIdx.x;
  const int b = bs >> 9;
  const int tid = threadIdx.x;
  const int tn = tid & 15, toc = tid >> 4;
  const float* xb = pcd + (size_t)b * NPTS * 3;
  const unsigned short* gl = glists + (size_t)bs * 176;

  const float cx = new_xyz[(size_t)bs * 3 + 0];
  const float cy = new_xyz[(size_t)bs * 3 + 1];
  const float cz = new_xyz[(size_t)bs * 3 + 2];

  // pad channel row (shared by all scales' first layers) — zero once
  if (tid < 68) cbuf[3 * 68 + tid] = 0.0f;
  // W0: stage c0 (cols 0-15) and c1 (cols 16-47): gl[tid] maps directly
  if (tid < 48) {
    int j = gl[tid];
    const float* p = xb + 3 * j;
    cbuf[0 * 68 + tid] = __fsub_rn(p[0], cx);
    cbuf[1 * 68 + tid] = __fsub_rn(p[1], cy);
    cbuf[2 * 68 + tid] = __fsub_rn(p[2], cz);
  }
  __syncthreads();

  // W1: L00  cbuf -> hB (stride 18)
  {
    float a[2][1]; ib<2, 1>(a, b00 + toc * 2);
    layer_acc<1, 2, 1, 68, 4>(wt + W00 + (toc * 2) * 4, cbuf, a, tn);
    store_relu<2, 1, 18>(hB + (toc * 2) * 18, a, tn);
  }
  __syncthreads();

  // W2: L01  hB -> hA (stride 18)
  {
    float a[2][1]; ib<2, 1>(a, b01 + toc * 2);
    layer_acc<8, 2, 1, 18, 32>(wt + W01 + (toc * 2) * 32, hB, a, tn);
    store_relu<2, 1, 18>(hA + (toc * 2) * 18, a, tn);
  }
  __syncthreads();

  // W3: L02 hA -> feat  ||  L10 cbuf+16 -> hB (stride 34)
  {
    float a[4][1]; ib<4, 1>(a, b02 + toc * 4);
    layer_acc<8, 4, 1, 18, 32>(wt + W02 + (toc * 4) * 32, hA, a, tn);
    float r[4] = {0.0f, 0.0f, 0.0f, 0.0f};
    rmax_upd<4, 1>(r, a);
    rmax_commit<4>(feat + toc * 4, r, tn);
    float a1[4][2]; ib<4, 2>(a1, b10 + toc * 4);
    layer_acc<1, 4, 2, 68, 4>(wt + W10 + (toc * 4) * 4, cbuf + 16, a1, tn);
    store_relu<4, 2, 34>(hB + (toc * 4) * 34, a1, tn);
  }
  __syncthreads();

  // W4: L11 hB -> hA (stride 34)  ||  stage c2 tile0 -> cbuf
  {
    float a[4][2]; ib<4, 2>(a, b11 + toc * 4);
    layer_acc<16, 4, 2, 34, 64>(wt + W11 + (toc * 4) * 64, hB, a, tn);
    store_relu<4, 2, 34>(hA + (toc * 4) * 34, a, tn);
    if (tid < 64) {
      int j = gl[48 + tid];
      const float* p = xb + 3 * j;
      cbuf[0 * 68 + tid] = __fsub_rn(p[0], cx);
      cbuf[1 * 68 + tid] = __fsub_rn(p[1], cy);
      cbuf[2 * 68 + tid] = __fsub_rn(p[2], cz);
    }
  }
  __syncthreads();

  // W5: L12 hA -> feat  ||  L20(t0) cbuf -> hB (stride 68)
  {
    float a[8][2]; ib<8, 2>(a, b12 + toc * 8);
    layer_acc<16, 8, 2, 34, 64>(wt + W12 + (toc * 8) * 64, hA, a, tn);
    float r[8] = {0.0f, 0.0f, 0.0f, 0.0f, 0.0f, 0.0f, 0.0f, 0.0f};
    rmax_upd<8, 2>(r, a);
    rmax_commit<8>(feat + 64 + toc * 8, r, tn);
    float a2[4][4]; ib<4, 4>(a2, b20 + toc * 4);
    layer_acc<1, 4, 4, 68, 4>(wt + W20 + (toc * 4) * 4, cbuf, a2, tn);
    store_relu<4, 4, 68>(hB + (toc * 4) * 68, a2, tn);
  }
  __syncthreads();

  float rm2[8] = {0.0f, 0.0f, 0.0f, 0.0f, 0.0f, 0.0f, 0.0f, 0.0f};

  // W6: L21(t0) hB -> hA (stride 68)  ||  stage c2 tile1 -> cbuf
  {
    float a[6][4]; ib<6, 4>(a, b21 + toc * 6);
    layer_acc<16, 6, 4, 68, 64>(wt + W21 + (toc * 6) * 64, hB, a, tn);
    store_relu<6, 4, 68>(hA + (toc * 6) * 68, a, tn);
    if (tid < 64) {
      int j = gl[112 + tid];
      const float* p = xb + 3 * j;
      cbuf[0 * 68 + tid] = __fsub_rn(p[0], cx);
      cbuf[1 * 68 + tid] = __fsub_rn(p[1], cy);
      cbuf[2 * 68 + tid] = __fsub_rn(p[2], cz);
    }
  }
  __syncthreads();

  // W7: L22(t0) hA -> rm2  ||  L20(t1) cbuf -> hB
  {
    float a[8][4]; ib<8, 4>(a, b22 + toc * 8);
    layer_acc<24, 8, 4, 68, 96>(wt + W22 + (toc * 8) * 96, hA, a, tn);
    rmax_upd<8, 4>(rm2, a);
    float a2[4][4]; ib<4, 4>(a2, b20 + toc * 4);
    layer_acc<1, 4, 4, 68, 4>(wt + W20 + (toc * 4) * 4, cbuf, a2, tn);
    store_relu<4, 4, 68>(hB + (toc * 4) * 68, a2, tn);
  }
  __syncthreads();

  // W8: L21(t1) hB -> hA
  {
    float a[6][4]; ib<6, 4>(a, b21 + toc * 6);
    layer_acc<16, 6, 4, 68, 64>(wt + W21 + (toc * 6) * 64, hB, a, tn);
    store_relu<6, 4, 68>(hA + (toc * 6) * 68, a, tn);
  }
  __syncthreads();

  // W9: L22(t1) hA -> rm2 -> feat
  {
    float a[8][4]; ib<8, 4>(a, b22 + toc * 8);
    layer_acc<24, 8, 4, 68, 96>(wt + W22 + (toc * 8) * 96, hA, a, tn);
    rmax_upd<8, 4>(rm2, a);
    rmax_commit<8>(feat + 192 + toc * 8, rm2, tn);
  }
  __syncthreads();

  // W10: final linear 320 -> 1
  if (tid < 64) {
    float s = 0.0f;
#pragma unroll
    for (int c = 0; c < 5; ++c) s += feat[tid + c * 64] * wf[tid + c * 64];
#pragma unroll
    for (int o = 32; o > 0; o >>= 1) s += __shfl_down(s, o);
    if (tid == 0) out[bs] = s + bf[0];
  }
}

extern "C" void kernel_launch(void* const* d_in, const int* in_sizes, int n_in,
                              void* d_out, int out_size, void* d_ws, size_t ws_size,
                              hipStream_t stream) {
  const float* pcd = (const float*)d_in[0];
  float* wsf = (float*)d_ws;
  float* new_xyz = wsf;                              // 12288 floats
  float* wt = wsf + 12288;                           // 34432 floats
  unsigned short* glists = (unsigned short*)(wsf + 46720);  // 4096*176 u16

  prep_kernel<<<(WT_TOTAL + 255) / 256, 256, 0, stream>>>(
      (const float*)d_in[1], (const float*)d_in[3], (const float*)d_in[5],
      (const float*)d_in[7], (const float*)d_in[9], (const float*)d_in[11],
      (const float*)d_in[13], (const float*)d_in[15], (const float*)d_in[17],
      wt);

  fps_kernel<<<BATCH, 256, 0, stream>>>(pcd, new_xyz);

  bq_kernel<<<BATCH * NSAMP, 256, 0, stream>>>(pcd, new_xyz, glists);

  msg_kernel<<<BATCH * NSAMP, 256, 0, stream>>>(
      pcd, new_xyz, wt, glists,
      (const float*)d_in[2],  (const float*)d_in[4],  (const float*)d_in[6],
      (const float*)d_in[8],  (const float*)d_in[10], (const float*)d_in[12],
      (const float*)d_in[14], (const float*)d_in[16], (const float*)d_in[18],
      (const float*)d_in[19], (const float*)d_in[20],
      (float*)d_out);
}

// Round 10
// 580.982 us; speedup vs baseline: 1.8795x; 1.3560x over previous
//
#include <hip/hip_runtime.h>

#define BATCH 8
#define NPTS 4096
#define NSAMP 512   // npoint = NPTS/8

#define ROW_SHR(n) (0x110 | (n))
#define ROW_BCAST15 0x142
#define ROW_BCAST31 0x143

// f32 max-combine via DPP. bound_ctrl holes deliver 0.0f — identity here
// because per-thread best distances are always >= 0.
template <int CTRL, int RMASK>
__device__ __forceinline__ float fmax_dpp(float x) {
  int t = __builtin_amdgcn_update_dpp(0, __float_as_int(x), CTRL, RMASK, 0xf, true);
  return fmaxf(x, __int_as_float(t));
}

// ---------------------------------------------------------------------------
// Weight prep: transpose each w[cin][cout] into wt[cout][cinp] (cin padded
// to a multiple of 4 with zeros) so MLP threads can float4-load weights.
// ---------------------------------------------------------------------------
__device__ __forceinline__ void tsec(int g, const float* __restrict__ w,
                                     float* __restrict__ wt, int cin, int cinp,
                                     int cout, int base) {
  int local = g - base;
  if (local < 0 || local >= cinp * cout) return;
  int oc = local / cinp, ic = local % cinp;
  wt[base + local] = (ic < cin) ? w[ic * cout + oc] : 0.0f;
}

#define W00 0
#define W01 128
#define W02 1152
#define W10 3200
#define W11 3456
#define W12 7552
#define W20 15744
#define W21 16000
#define W22 22144
#define WT_TOTAL 34432

__global__ __launch_bounds__(256) void prep_kernel(
    const float* w00, const float* w01, const float* w02,
    const float* w10, const float* w11, const float* w12,
    const float* w20, const float* w21, const float* w22,
    float* __restrict__ wt) {
  int g = blockIdx.x * 256 + threadIdx.x;
  tsec(g, w00, wt, 3, 4, 32, W00);
  tsec(g, w01, wt, 32, 32, 32, W01);
  tsec(g, w02, wt, 32, 32, 64, W02);
  tsec(g, w10, wt, 3, 4, 64, W10);
  tsec(g, w11, wt, 64, 64, 64, W11);
  tsec(g, w12, wt, 64, 64, 128, W12);
  tsec(g, w20, wt, 3, 4, 64, W20);
  tsec(g, w21, wt, 64, 64, 96, W21);
  tsec(g, w22, wt, 96, 96, 128, W22);
}

// ---------------------------------------------------------------------------
// MLP building blocks (16 n-threads x 16 oc-threads). Input-channel
// accumulation order is sequential 0..CIN-1 => bitwise identical to ref.
// ---------------------------------------------------------------------------
template <int TOC, int TN>
__device__ __forceinline__ void ib(float (&acc)[TOC][TN], const float* bias) {
#pragma unroll
  for (int j = 0; j < TOC; ++j) {
    float bj = bias[j];
#pragma unroll
    for (int i = 0; i < TN; ++i) acc[j][i] = bj;
  }
}

template <int CIN4, int TOC, int TN, int NTPI, int WS>
__device__ __forceinline__ void layer_acc(const float* __restrict__ wtb,
                                          const float* hin,
                                          float (&acc)[TOC][TN], int tn) {
#pragma unroll 2
  for (int c4 = 0; c4 < CIN4; ++c4) {
    float hv[4][TN];
#pragma unroll
    for (int k = 0; k < 4; ++k) {
      const float* src = &hin[(c4 * 4 + k) * NTPI + tn * TN];
      if constexpr (TN == 1) {
        hv[k][0] = src[0];
      } else if constexpr (TN == 2) {
        float2 v = *(const float2*)src; hv[k][0] = v.x; hv[k][1] = v.y;
      } else {
        float4 v = *(const float4*)src;
        hv[k][0] = v.x; hv[k][1] = v.y; hv[k][2] = v.z; hv[k][3] = v.w;
      }
    }
#pragma unroll
    for (int j = 0; j < TOC; ++j) {
      float4 w4 = *(const float4*)&wtb[j * WS + c4 * 4];
#pragma unroll
      for (int i = 0; i < TN; ++i) {
        acc[j][i] = fmaf(hv[0][i], w4.x, acc[j][i]);
        acc[j][i] = fmaf(hv[1][i], w4.y, acc[j][i]);
        acc[j][i] = fmaf(hv[2][i], w4.z, acc[j][i]);
        acc[j][i] = fmaf(hv[3][i], w4.w, acc[j][i]);
      }
    }
  }
}

template <int TOC, int TN, int NTPO>
__device__ __forceinline__ void store_relu(float* hout,   // + ocrow*NTPO
                                           float (&acc)[TOC][TN], int tn) {
#pragma unroll
  for (int j = 0; j < TOC; ++j) {
    float* dst = &hout[j * NTPO + tn * TN];
    if constexpr (TN == 1) {
      dst[0] = fmaxf(acc[j][0], 0.0f);
    } else if constexpr (TN == 2) {
      *(float2*)dst = make_float2(fmaxf(acc[j][0], 0.0f),
                                  fmaxf(acc[j][1], 0.0f));
    } else {
      *(float4*)dst = make_float4(fmaxf(acc[j][0], 0.0f),
                                  fmaxf(acc[j][1], 0.0f),
                                  fmaxf(acc[j][2], 0.0f),
                                  fmaxf(acc[j][3], 0.0f));
    }
  }
}

template <int TOC, int TN>
__device__ __forceinline__ void rmax_upd(float (&r)[TOC],
                                         float (&acc)[TOC][TN]) {
#pragma unroll
  for (int j = 0; j < TOC; ++j) {
    float m = 0.0f;   // relu floor
#pragma unroll
    for (int i = 0; i < TN; ++i) m = fmaxf(m, acc[j][i]);
    r[j] = fmaxf(r[j], m);
  }
}

template <int TOC>
__device__ __forceinline__ void rmax_commit(float* fdst, float (&r)[TOC],
                                            int tn) {
#pragma unroll
  for (int j = 0; j < TOC; ++j) {
    float v = r[j];
    v = fmaxf(v, __shfl_xor(v, 1));
    v = fmaxf(v, __shfl_xor(v, 2));
    v = fmaxf(v, __shfl_xor(v, 4));
    v = fmaxf(v, __shfl_xor(v, 8));
    if (tn == 0) fdst[j] = v;
  }
}

// ---------------------------------------------------------------------------
// Fused pipelined kernel. Every block takes a ticket; tickets 0..7 run FPS
// for batch=ticket (producers), the rest are per-sample consumers
// (s = tk>>3, b = tk&7 so early tickets serve early samples of ALL batches).
// Claim-based roles => producers are always among the first scheduled
// blocks, so consumers' spin-waits cannot deadlock (G16-safe: device-scope
// atomics, release/acquire, no dispatch-order assumptions).
// ---------------------------------------------------------------------------
__global__ __launch_bounds__(256) void fused_kernel(
    const float* __restrict__ pcd, float* __restrict__ new_xyz,
    int* __restrict__ ctrl, const float* __restrict__ wt,
    const float* __restrict__ b00, const float* __restrict__ b01,
    const float* __restrict__ b02, const float* __restrict__ b10,
    const float* __restrict__ b11, const float* __restrict__ b12,
    const float* __restrict__ b20, const float* __restrict__ b21,
    const float* __restrict__ b22,
    const float* __restrict__ wf, const float* __restrict__ bf,
    float* __restrict__ out) {
  __shared__ __align__(16) float lds[11952];   // 47808 B -> 3 blocks/CU
  __shared__ int s_ticket;

  const int tid = threadIdx.x;
  int* progress = ctrl + 8;

  if (tid == 0) s_ticket = atomicAdd(&ctrl[0], 1);
  __syncthreads();
  const int ticket = s_ticket;

  if (ticket < BATCH) {
    // ================= producer: FPS for batch = ticket =================
    const int b = ticket;
    const int t = tid;
    const int wave = t >> 6, lane = t & 63;
    const float* xb = pcd + (size_t)b * NPTS * 3;
    float4* slot = (float4*)lds;               // [2][4] parity dbuf

    float X[16], Y[16], Z[16], mind[16];
    {
      float f[48];
      float4* vv = (float4*)f;
      const float4* src = (const float4*)xb + t * 12;   // 192 B/thread
#pragma unroll
      for (int q = 0; q < 12; ++q) vv[q] = src[q];
#pragma unroll
      for (int j = 0; j < 16; ++j) {
        X[j] = f[3 * j + 0]; Y[j] = f[3 * j + 1]; Z[j] = f[3 * j + 2];
        mind[j] = 10000000000.0f;
      }
    }
    float px = xb[0], py = xb[1], pz = xb[2];   // first sample is index 0

    for (int it = 0; it < NSAMP; ++it) {
      if (t == 0) {
        int* dst = (int*)(new_xyz + ((size_t)b * NSAMP + it) * 3);
        atomicExch(&dst[0], __float_as_int(px));   // device-scope, coherent
        atomicExch(&dst[1], __float_as_int(py));
        atomicExch(&dst[2], __float_as_int(pz));
        if ((it & 7) == 7)                          // NSAMP % 8 == 0
          __hip_atomic_store(&progress[b], it + 1, __ATOMIC_RELEASE,
                             __HIP_MEMORY_SCOPE_AGENT);
      }
      // ---- update min-dist + local argmax (strict > = first occurrence),
      //      tracking winner coords in registers (exact fp32, no FMA) ----
      float bv = -1.0f, bx = 0.0f, by = 0.0f, bz = 0.0f;
#pragma unroll
      for (int j = 0; j < 16; ++j) {
        float dx = __fsub_rn(X[j], px);
        float dy = __fsub_rn(Y[j], py);
        float dz = __fsub_rn(Z[j], pz);
        float d = __fadd_rn(__fadd_rn(__fmul_rn(dx, dx), __fmul_rn(dy, dy)),
                            __fmul_rn(dz, dz));
        float m = fminf(mind[j], d);
        mind[j] = m;
        bool g = m > bv;
        bv = g ? m : bv;
        bx = g ? X[j] : bx; by = g ? Y[j] : by; bz = g ? Z[j] : bz;
      }
      // ---- wave max via f32 DPP; ballot+ffs -> exact lowest-index winner
      float m6 = bv;
      m6 = fmax_dpp<ROW_SHR(1), 0xf>(m6);
      m6 = fmax_dpp<ROW_SHR(2), 0xf>(m6);
      m6 = fmax_dpp<ROW_SHR(4), 0xf>(m6);
      m6 = fmax_dpp<ROW_SHR(8), 0xf>(m6);
      m6 = fmax_dpp<ROW_BCAST15, 0xa>(m6);
      m6 = fmax_dpp<ROW_BCAST31, 0xc>(m6);
      float wmax = __int_as_float(
          __builtin_amdgcn_readlane(__float_as_int(m6), 63));
      unsigned long long msk = __ballot(bv == wmax);
      if (lane == __ffsll(msk) - 1)
        slot[(it & 1) * 4 + wave] = make_float4(bx, by, bz, wmax);
      __syncthreads();
      // ---- cross-wave combine; strict > keeps lowest wave = lowest idx --
      float4 cur = slot[(it & 1) * 4 + 0];
#pragma unroll
      for (int w = 1; w < 4; ++w) {
        float4 sw = slot[(it & 1) * 4 + w];
        if (sw.w > cur.w) cur = sw;
      }
      px = cur.x; py = cur.y; pz = cur.z;
    }
    return;
  }

  // ================= consumer: ball query + MLPs for one sample =========
  const int tk = ticket - BATCH;
  const int b = tk & 7;
  const int s = tk >> 3;
  const int bs = (b << 9) | s;
  const int lane = tid & 63;
  const int wave = tid >> 6;
  const int tn = tid & 15, toc = tid >> 4;
  const float* xb = pcd + (size_t)b * NPTS * 3;

  float* hA = lds;                                        // 96*68
  float* hB = lds + 6528;                                 // 64*68
  float* cbuf = lds + 10880;                              // 4*68
  float* feat = lds + 11152;                              // 320
  unsigned long long* masks = (unsigned long long*)(lds + 11472);  // [3][64]
  unsigned short* gl = (unsigned short*)(lds + 11856);    // [176]
  float* bc = lds + 11944;                                // center bcast

  // ---- wait for this sample's center (thread 0 spins, then broadcasts) --
  if (tid == 0) {
    while (__hip_atomic_load(&progress[b], __ATOMIC_ACQUIRE,
                             __HIP_MEMORY_SCOPE_AGENT) <= s)
      __builtin_amdgcn_s_sleep(2);
    const int* src = (const int*)(new_xyz + (size_t)bs * 3);
    bc[0] = __int_as_float(__hip_atomic_load(&src[0], __ATOMIC_RELAXED,
                                             __HIP_MEMORY_SCOPE_AGENT));
    bc[1] = __int_as_float(__hip_atomic_load(&src[1], __ATOMIC_RELAXED,
                                             __HIP_MEMORY_SCOPE_AGENT));
    bc[2] = __int_as_float(__hip_atomic_load(&src[2], __ATOMIC_RELAXED,
                                             __HIP_MEMORY_SCOPE_AGENT));
  }
  __syncthreads();
  const float cx = bc[0], cy = bc[1], cz = bc[2];

  // ---- ball query phase 1: in-radius bitmasks (3 radii x 64 chunks) ----
  const float r2a = (float)(0.1 * 0.1);
  const float r2b = (float)(0.2 * 0.2);
  const float r2c = (float)(0.4 * 0.4);
#pragma unroll 4
  for (int j = 0; j < 16; ++j) {
    int i = (j << 8) | tid;
    const float* p = xb + i * 3;
    float dx = __fsub_rn(cx, p[0]);
    float dy = __fsub_rn(cy, p[1]);
    float dz = __fsub_rn(cz, p[2]);
    float sq = __fadd_rn(__fadd_rn(__fmul_rn(dx, dx), __fmul_rn(dy, dy)),
                         __fmul_rn(dz, dz));
    unsigned long long m0 = __ballot(sq < r2a);
    unsigned long long m1 = __ballot(sq < r2b);
    unsigned long long m2 = __ballot(sq < r2c);
    if (lane == 0) {
      int c = (j << 2) | wave;
      masks[0 * 64 + c] = m0; masks[1 * 64 + c] = m1; masks[2 * 64 + c] = m2;
    }
  }
  __syncthreads();

  // ---- ball query phase 2: wave s builds ordered padded list ----
  if (wave < 3) {
    const int ns  = (wave == 0) ? 16 : (wave == 1) ? 32 : 128;
    const int off = (wave == 0) ? 0  : (wave == 1) ? 16 : 48;
    unsigned long long m = masks[wave * 64 + lane];
    int pc = (int)__popcll(m);
    int incl = pc;
#pragma unroll
    for (int o = 1; o < 64; o <<= 1) {
      int u = __shfl_up(incl, o);
      if (lane >= o) incl += u;
    }
    int ex = incl - pc;
    int total = __shfl(incl, 63);
    unsigned short* glw = gl + off;
    unsigned long long mm = m;
    int p = ex;
    while (mm && p < ns) {
      int l = (int)__builtin_ctzll(mm);
      mm &= mm - 1;
      glw[p++] = (unsigned short)((lane << 6) | l);
    }
    int cnt = total < ns ? total : ns;
    unsigned long long nz = __ballot(pc > 0);
    int fl = __ffsll(nz) - 1;                   // center guarantees nz != 0
    int myf = (lane << 6) | (int)__builtin_ctzll(m | 0x8000000000000000ull);
    int fidx = __shfl(myf, fl);
    for (int k = cnt + lane; k < ns; k += 64) glw[k] = (unsigned short)fidx;
  }
  __syncthreads();

  // W0: pad row + stage c0 (cols 0-15) and c1 (cols 16-47)
  if (tid < 68) cbuf[3 * 68 + tid] = 0.0f;
  if (tid < 48) {
    int j = gl[tid];
    const float* p = xb + 3 * j;
    cbuf[0 * 68 + tid] = __fsub_rn(p[0], cx);
    cbuf[1 * 68 + tid] = __fsub_rn(p[1], cy);
    cbuf[2 * 68 + tid] = __fsub_rn(p[2], cz);
  }
  __syncthreads();

  // W1: L00  cbuf -> hB (stride 18)
  {
    float a[2][1]; ib<2, 1>(a, b00 + toc * 2);
    layer_acc<1, 2, 1, 68, 4>(wt + W00 + (toc * 2) * 4, cbuf, a, tn);
    store_relu<2, 1, 18>(hB + (toc * 2) * 18, a, tn);
  }
  __syncthreads();

  // W2: L01  hB -> hA (stride 18)
  {
    float a[2][1]; ib<2, 1>(a, b01 + toc * 2);
    layer_acc<8, 2, 1, 18, 32>(wt + W01 + (toc * 2) * 32, hB, a, tn);
    store_relu<2, 1, 18>(hA + (toc * 2) * 18, a, tn);
  }
  __syncthreads();

  // W3: L02 hA -> feat  ||  L10 cbuf+16 -> hB (stride 34)
  {
    float a[4][1]; ib<4, 1>(a, b02 + toc * 4);
    layer_acc<8, 4, 1, 18, 32>(wt + W02 + (toc * 4) * 32, hA, a, tn);
    float r[4] = {0.0f, 0.0f, 0.0f, 0.0f};
    rmax_upd<4, 1>(r, a);
    rmax_commit<4>(feat + toc * 4, r, tn);
    float a1[4][2]; ib<4, 2>(a1, b10 + toc * 4);
    layer_acc<1, 4, 2, 68, 4>(wt + W10 + (toc * 4) * 4, cbuf + 16, a1, tn);
    store_relu<4, 2, 34>(hB + (toc * 4) * 34, a1, tn);
  }
  __syncthreads();

  // W4: L11 hB -> hA (stride 34)  ||  stage c2 tile0 -> cbuf
  {
    float a[4][2]; ib<4, 2>(a, b11 + toc * 4);
    layer_acc<16, 4, 2, 34, 64>(wt + W11 + (toc * 4) * 64, hB, a, tn);
    store_relu<4, 2, 34>(hA + (toc * 4) * 34, a, tn);
    if (tid < 64) {
      int j = gl[48 + tid];
      const float* p = xb + 3 * j;
      cbuf[0 * 68 + tid] = __fsub_rn(p[0], cx);
      cbuf[1 * 68 + tid] = __fsub_rn(p[1], cy);
      cbuf[2 * 68 + tid] = __fsub_rn(p[2], cz);
    }
  }
  __syncthreads();

  // W5: L12 hA -> feat  ||  L20(t0) cbuf -> hB (stride 68)
  {
    float a[8][2]; ib<8, 2>(a, b12 + toc * 8);
    layer_acc<16, 8, 2, 34, 64>(wt + W12 + (toc * 8) * 64, hA, a, tn);
    float r[8] = {0.0f, 0.0f, 0.0f, 0.0f, 0.0f, 0.0f, 0.0f, 0.0f};
    rmax_upd<8, 2>(r, a);
    rmax_commit<8>(feat + 64 + toc * 8, r, tn);
    float a2[4][4]; ib<4, 4>(a2, b20 + toc * 4);
    layer_acc<1, 4, 4, 68, 4>(wt + W20 + (toc * 4) * 4, cbuf, a2, tn);
    store_relu<4, 4, 68>(hB + (toc * 4) * 68, a2, tn);
  }
  __syncthreads();

  float rm2[8] = {0.0f, 0.0f, 0.0f, 0.0f, 0.0f, 0.0f, 0.0f, 0.0f};

  // W6: L21(t0) hB -> hA (stride 68)  ||  stage c2 tile1 -> cbuf
  {
    float a[6][4]; ib<6, 4>(a, b21 + toc * 6);
    layer_acc<16, 6, 4, 68, 64>(wt + W21 + (toc * 6) * 64, hB, a, tn);
    store_relu<6, 4, 68>(hA + (toc * 6) * 68, a, tn);
    if (tid < 64) {
      int j = gl[112 + tid];
      const float* p = xb + 3 * j;
      cbuf[0 * 68 + tid] = __fsub_rn(p[0], cx);
      cbuf[1 * 68 + tid] = __fsub_rn(p[1], cy);
      cbuf[2 * 68 + tid] = __fsub_rn(p[2], cz);
    }
  }
  __syncthreads();

  // W7: L22(t0) hA -> rm2  ||  L20(t1) cbuf -> hB
  {
    float a[8][4]; ib<8, 4>(a, b22 + toc * 8);
    layer_acc<24, 8, 4, 68, 96>(wt + W22 + (toc * 8) * 96, hA, a, tn);
    rmax_upd<8, 4>(rm2, a);
    float a2[4][4]; ib<4, 4>(a2, b20 + toc * 4);
    layer_acc<1, 4, 4, 68, 4>(wt + W20 + (toc * 4) * 4, cbuf, a2, tn);
    store_relu<4, 4, 68>(hB + (toc * 4) * 68, a2, tn);
  }
  __syncthreads();

  // W8: L21(t1) hB -> hA
  {
    float a[6][4]; ib<6, 4>(a, b21 + toc * 6);
    layer_acc<16, 6, 4, 68, 64>(wt + W21 + (toc * 6) * 64, hB, a, tn);
    store_relu<6, 4, 68>(hA + (toc * 6) * 68, a, tn);
  }
  __syncthreads();

  // W9: L22(t1) hA -> rm2 -> feat
  {
    float a[8][4]; ib<8, 4>(a, b22 + toc * 8);
    layer_acc<24, 8, 4, 68, 96>(wt + W22 + (toc * 8) * 96, hA, a, tn);
    rmax_upd<8, 4>(rm2, a);
    rmax_commit<8>(feat + 192 + toc * 8, rm2, tn);
  }
  __syncthreads();

  // W10: final linear 320 -> 1
  if (tid < 64) {
    float sacc = 0.0f;
#pragma unroll
    for (int c = 0; c < 5; ++c) sacc += feat[tid + c * 64] * wf[tid + c * 64];
#pragma unroll
    for (int o = 32; o > 0; o >>= 1) sacc += __shfl_down(sacc, o);
    if (tid == 0) out[bs] = sacc + bf[0];
  }
}

extern "C" void kernel_launch(void* const* d_in, const int* in_sizes, int n_in,
                              void* d_out, int out_size, void* d_ws, size_t ws_size,
                              hipStream_t stream) {
  const float* pcd = (const float*)d_in[0];
  float* wsf = (float*)d_ws;
  float* new_xyz = wsf;                 // 12288 floats
  float* wt = wsf + 12288;              // 34432 floats
  int* ctrl = (int*)(wsf + 46720);      // [0]=claim, [8..15]=progress

  hipMemsetAsync(ctrl, 0, 64, stream);

  prep_kernel<<<(WT_TOTAL + 255) / 256, 256, 0, stream>>>(
      (const float*)d_in[1], (const float*)d_in[3], (const float*)d_in[5],
      (const float*)d_in[7], (const float*)d_in[9], (const float*)d_in[11],
      (const float*)d_in[13], (const float*)d_in[15], (const float*)d_in[17],
      wt);

  fused_kernel<<<BATCH * NSAMP + BATCH, 256, 0, stream>>>(
      pcd, new_xyz, ctrl, wt,
      (const float*)d_in[2],  (const float*)d_in[4],  (const float*)d_in[6],
      (const float*)d_in[8],  (const float*)d_in[10], (const float*)d_in[12],
      (const float*)d_in[14], (const float*)d_in[16], (const float*)d_in[18],
      (const float*)d_in[19], (const float*)d_in[20],
      (float*)d_out);
}

// Round 11
// 504.085 us; speedup vs baseline: 2.1662x; 1.1525x over previous
//
#include <hip/hip_runtime.h>

#define BATCH 8
#define NPTS 4096
#define NSAMP 512   // npoint = NPTS/8

#define ROW_SHR(n) (0x110 | (n))
#define ROW_BCAST15 0x142
#define ROW_BCAST31 0x143

// f32 max-combine via DPP. bound_ctrl holes deliver 0.0f — identity for
// values >= 0 (distances / relu outputs).
template <int CTRL, int RMASK>
__device__ __forceinline__ float fmax_dpp(float x) {
  int t = __builtin_amdgcn_update_dpp(0, __float_as_int(x), CTRL, RMASK, 0xf, true);
  return fmaxf(x, __int_as_float(t));
}

// wave max (result valid in lane 63), values >= 0
__device__ __forceinline__ float wave_max(float x) {
  x = fmax_dpp<ROW_SHR(1), 0xf>(x);
  x = fmax_dpp<ROW_SHR(2), 0xf>(x);
  x = fmax_dpp<ROW_SHR(4), 0xf>(x);
  x = fmax_dpp<ROW_SHR(8), 0xf>(x);
  x = fmax_dpp<ROW_BCAST15, 0xa>(x);
  x = fmax_dpp<ROW_BCAST31, 0xc>(x);
  return x;
}

// ---------------------------------------------------------------------------
// Weight prep: transpose w[cin][cout] -> wt[cout][cinp] (cin padded to x4)
// for the 16x16-scheme layers (scales 0/1 and L20).
// ---------------------------------------------------------------------------
__device__ __forceinline__ void tsec(int g, const float* __restrict__ w,
                                     float* __restrict__ wt, int cin, int cinp,
                                     int cout, int base) {
  int local = g - base;
  if (local < 0 || local >= cinp * cout) return;
  int oc = local / cinp, ic = local % cinp;
  wt[base + local] = (ic < cin) ? w[ic * cout + oc] : 0.0f;
}

#define W00 0
#define W01 128
#define W02 1152
#define W10 3200
#define W11 3456
#define W12 7552
#define W20 15744
#define WT_TOTAL 16000

__global__ __launch_bounds__(256) void prep_kernel(
    const float* w00, const float* w01, const float* w02,
    const float* w10, const float* w11, const float* w12,
    const float* w20, float* __restrict__ wt) {
  int g = blockIdx.x * 256 + threadIdx.x;
  tsec(g, w00, wt, 3, 4, 32, W00);
  tsec(g, w01, wt, 32, 32, 32, W01);
  tsec(g, w02, wt, 32, 32, 64, W02);
  tsec(g, w10, wt, 3, 4, 64, W10);
  tsec(g, w11, wt, 64, 64, 64, W11);
  tsec(g, w12, wt, 64, 64, 128, W12);
  tsec(g, w20, wt, 3, 4, 64, W20);
}

// ---------------------------------------------------------------------------
// 16x16-scheme MLP building blocks (16 n-threads x 16 oc-threads).
// Input-channel order is sequential 0..CIN-1 => bitwise identical to ref.
// ---------------------------------------------------------------------------
template <int TOC, int TN>
__device__ __forceinline__ void ib(float (&acc)[TOC][TN], const float* bias) {
#pragma unroll
  for (int j = 0; j < TOC; ++j) {
    float bj = bias[j];
#pragma unroll
    for (int i = 0; i < TN; ++i) acc[j][i] = bj;
  }
}

template <int CIN4, int TOC, int TN, int NTPI, int WS>
__device__ __forceinline__ void layer_acc(const float* __restrict__ wtb,
                                          const float* hin,
                                          float (&acc)[TOC][TN], int tn) {
#pragma unroll 2
  for (int c4 = 0; c4 < CIN4; ++c4) {
    float hv[4][TN];
#pragma unroll
    for (int k = 0; k < 4; ++k) {
      const float* src = &hin[(c4 * 4 + k) * NTPI + tn * TN];
      if constexpr (TN == 1) {
        hv[k][0] = src[0];
      } else if constexpr (TN == 2) {
        float2 v = *(const float2*)src; hv[k][0] = v.x; hv[k][1] = v.y;
      } else {
        float4 v = *(const float4*)src;
        hv[k][0] = v.x; hv[k][1] = v.y; hv[k][2] = v.z; hv[k][3] = v.w;
      }
    }
#pragma unroll
    for (int j = 0; j < TOC; ++j) {
      float4 w4 = *(const float4*)&wtb[j * WS + c4 * 4];
#pragma unroll
      for (int i = 0; i < TN; ++i) {
        acc[j][i] = fmaf(hv[0][i], w4.x, acc[j][i]);
        acc[j][i] = fmaf(hv[1][i], w4.y, acc[j][i]);
        acc[j][i] = fmaf(hv[2][i], w4.z, acc[j][i]);
        acc[j][i] = fmaf(hv[3][i], w4.w, acc[j][i]);
      }
    }
  }
}

template <int TOC, int TN, int NTPO>
__device__ __forceinline__ void store_relu(float* hout,
                                           float (&acc)[TOC][TN], int tn) {
#pragma unroll
  for (int j = 0; j < TOC; ++j) {
    float* dst = &hout[j * NTPO + tn * TN];
    if constexpr (TN == 1) {
      dst[0] = fmaxf(acc[j][0], 0.0f);
    } else if constexpr (TN == 2) {
      *(float2*)dst = make_float2(fmaxf(acc[j][0], 0.0f),
                                  fmaxf(acc[j][1], 0.0f));
    } else {
      *(float4*)dst = make_float4(fmaxf(acc[j][0], 0.0f),
                                  fmaxf(acc[j][1], 0.0f),
                                  fmaxf(acc[j][2], 0.0f),
                                  fmaxf(acc[j][3], 0.0f));
    }
  }
}

template <int TOC, int TN>
__device__ __forceinline__ void rmax_upd(float (&r)[TOC],
                                         float (&acc)[TOC][TN]) {
#pragma unroll
  for (int j = 0; j < TOC; ++j) {
    float m = 0.0f;
#pragma unroll
    for (int i = 0; i < TN; ++i) m = fmaxf(m, acc[j][i]);
    r[j] = fmaxf(r[j], m);
  }
}

template <int TOC>
__device__ __forceinline__ void rmax_commit(float* fdst, float (&r)[TOC],
                                            int tn) {
#pragma unroll
  for (int j = 0; j < TOC; ++j) {
    float v = r[j];
    v = fmaxf(v, __shfl_xor(v, 1));
    v = fmaxf(v, __shfl_xor(v, 2));
    v = fmaxf(v, __shfl_xor(v, 4));
    v = fmaxf(v, __shfl_xor(v, 8));
    if (tn == 0) fdst[j] = v;
  }
}

// ---------------------------------------------------------------------------
// Fused pipelined kernel (producer FPS blocks + per-sample consumers).
// LDS map (floats), 11264 total (45 KB -> 3 blocks/CU):
//   h1   @     0 [64][64]   L20 out
//   h2   @  4096 [96][64]   L21 out   (sB@4096, sA@6272 alias here pre-W6)
//   cbuf @ 10240 [4][68], cbuf2 @ 10512 [4][68]
//   feat @ 10784 [320]      (masks[3][64] u64 alias here during bq)
//   gl   @ 11168 [176 u16], bc @ 11256
// ---------------------------------------------------------------------------
__global__ __launch_bounds__(256) void fused_kernel(
    const float* __restrict__ pcd, float* __restrict__ new_xyz,
    int* __restrict__ ctrl, const float* __restrict__ wt,
    const float* __restrict__ w21o, const float* __restrict__ w22o,
    const float* __restrict__ b00, const float* __restrict__ b01,
    const float* __restrict__ b02, const float* __restrict__ b10,
    const float* __restrict__ b11, const float* __restrict__ b12,
    const float* __restrict__ b20, const float* __restrict__ b21,
    const float* __restrict__ b22,
    const float* __restrict__ wf, const float* __restrict__ bf,
    float* __restrict__ out) {
  __shared__ __align__(16) float lds[11264];
  __shared__ int s_ticket;

  const int tid = threadIdx.x;
  int* progress = ctrl + 8;

  if (tid == 0) s_ticket = atomicAdd(&ctrl[0], 1);
  __syncthreads();
  const int ticket = s_ticket;

  if (ticket < BATCH) {
    // ================= producer: FPS for batch = ticket =================
    const int b = ticket;
    const int t = tid;
    const int wave = t >> 6, lane = t & 63;
    const float* xb = pcd + (size_t)b * NPTS * 3;
    float4* slot = (float4*)lds;               // [2][4] parity dbuf

    float X[16], Y[16], Z[16], mind[16];
    {
      float f[48];
      float4* vv = (float4*)f;
      const float4* src = (const float4*)xb + t * 12;
#pragma unroll
      for (int q = 0; q < 12; ++q) vv[q] = src[q];
#pragma unroll
      for (int j = 0; j < 16; ++j) {
        X[j] = f[3 * j + 0]; Y[j] = f[3 * j + 1]; Z[j] = f[3 * j + 2];
        mind[j] = 10000000000.0f;
      }
    }
    float px = xb[0], py = xb[1], pz = xb[2];

    for (int it = 0; it < NSAMP; ++it) {
      if (t == 0) {
        int* dst = (int*)(new_xyz + ((size_t)b * NSAMP + it) * 3);
        atomicExch(&dst[0], __float_as_int(px));
        atomicExch(&dst[1], __float_as_int(py));
        atomicExch(&dst[2], __float_as_int(pz));
        if ((it & 7) == 7)
          __hip_atomic_store(&progress[b], it + 1, __ATOMIC_RELEASE,
                             __HIP_MEMORY_SCOPE_AGENT);
      }
      float bv = -1.0f, bx = 0.0f, by = 0.0f, bz = 0.0f;
#pragma unroll
      for (int j = 0; j < 16; ++j) {
        float dx = __fsub_rn(X[j], px);
        float dy = __fsub_rn(Y[j], py);
        float dz = __fsub_rn(Z[j], pz);
        float d = __fadd_rn(__fadd_rn(__fmul_rn(dx, dx), __fmul_rn(dy, dy)),
                            __fmul_rn(dz, dz));
        float m = fminf(mind[j], d);
        mind[j] = m;
        bool g = m > bv;
        bv = g ? m : bv;
        bx = g ? X[j] : bx; by = g ? Y[j] : by; bz = g ? Z[j] : bz;
      }
      float wmax = __int_as_float(
          __builtin_amdgcn_readlane(__float_as_int(wave_max(bv)), 63));
      unsigned long long msk = __ballot(bv == wmax);
      if (lane == __ffsll(msk) - 1)
        slot[(it & 1) * 4 + wave] = make_float4(bx, by, bz, wmax);
      __syncthreads();
      float4 cur = slot[(it & 1) * 4 + 0];
#pragma unroll
      for (int w = 1; w < 4; ++w) {
        float4 sw = slot[(it & 1) * 4 + w];
        if (sw.w > cur.w) cur = sw;
      }
      px = cur.x; py = cur.y; pz = cur.z;
    }
    return;
  }

  // ================= consumer: ball query + MLPs for one sample =========
  const int tk = ticket - BATCH;
  const int b = tk & 7;
  const int s = tk >> 3;
  const int bs = (b << 9) | s;
  const int lane = tid & 63;
  const int wave = tid >> 6;
  const int tn = tid & 15, toc = tid >> 4;
  const float* xb = pcd + (size_t)b * NPTS * 3;

  float* h1 = lds;                                        // [64][64]
  float* h2 = lds + 4096;                                 // [96][64]
  float* sB = lds + 4096;                                 // alias (pre-W6)
  float* sA = lds + 6272;                                 // alias (pre-W6)
  float* cbuf  = lds + 10240;                             // [4][68]
  float* cbuf2 = lds + 10512;                             // [4][68]
  float* feat = lds + 10784;                              // [320]
  unsigned long long* masks = (unsigned long long*)(lds + 10784);  // alias
  unsigned short* gl = (unsigned short*)(lds + 11168);    // [176]
  float* bc = lds + 11256;

  if (tid == 0) {
    while (__hip_atomic_load(&progress[b], __ATOMIC_ACQUIRE,
                             __HIP_MEMORY_SCOPE_AGENT) <= s)
      __builtin_amdgcn_s_sleep(2);
    const int* src = (const int*)(new_xyz + (size_t)bs * 3);
    bc[0] = __int_as_float(__hip_atomic_load(&src[0], __ATOMIC_RELAXED,
                                             __HIP_MEMORY_SCOPE_AGENT));
    bc[1] = __int_as_float(__hip_atomic_load(&src[1], __ATOMIC_RELAXED,
                                             __HIP_MEMORY_SCOPE_AGENT));
    bc[2] = __int_as_float(__hip_atomic_load(&src[2], __ATOMIC_RELAXED,
                                             __HIP_MEMORY_SCOPE_AGENT));
  }
  __syncthreads();
  const float cx = bc[0], cy = bc[1], cz = bc[2];

  // ---- P1: in-radius bitmasks (3 radii x 64 chunks) ----
  const float r2a = (float)(0.1 * 0.1);
  const float r2b = (float)(0.2 * 0.2);
  const float r2c = (float)(0.4 * 0.4);
#pragma unroll 4
  for (int j = 0; j < 16; ++j) {
    int i = (j << 8) | tid;
    const float* p = xb + i * 3;
    float dx = __fsub_rn(cx, p[0]);
    float dy = __fsub_rn(cy, p[1]);
    float dz = __fsub_rn(cz, p[2]);
    float sq = __fadd_rn(__fadd_rn(__fmul_rn(dx, dx), __fmul_rn(dy, dy)),
                         __fmul_rn(dz, dz));
    unsigned long long m0 = __ballot(sq < r2a);
    unsigned long long m1 = __ballot(sq < r2b);
    unsigned long long m2 = __ballot(sq < r2c);
    if (lane == 0) {
      int c = (j << 2) | wave;
      masks[0 * 64 + c] = m0; masks[1 * 64 + c] = m1; masks[2 * 64 + c] = m2;
    }
  }
  __syncthreads();

  // ---- P2: wave s builds ordered padded list for scale s ----
  if (wave < 3) {
    const int ns  = (wave == 0) ? 16 : (wave == 1) ? 32 : 128;
    const int off = (wave == 0) ? 0  : (wave == 1) ? 16 : 48;
    unsigned long long m = masks[wave * 64 + lane];
    int pc = (int)__popcll(m);
    int incl = pc;
#pragma unroll
    for (int o = 1; o < 64; o <<= 1) {
      int u = __shfl_up(incl, o);
      if (lane >= o) incl += u;
    }
    int ex = incl - pc;
    int total = __shfl(incl, 63);
    unsigned short* glw = gl + off;
    unsigned long long mm = m;
    int p = ex;
    while (mm && p < ns) {
      int l = (int)__builtin_ctzll(mm);
      mm &= mm - 1;
      glw[p++] = (unsigned short)((lane << 6) | l);
    }
    int cnt = total < ns ? total : ns;
    unsigned long long nz = __ballot(pc > 0);
    int fl = __ffsll(nz) - 1;
    int myf = (lane << 6) | (int)__builtin_ctzll(m | 0x8000000000000000ull);
    int fidx = __shfl(myf, fl);
    for (int k = cnt + lane; k < ns; k += 64) glw[k] = (unsigned short)fidx;
  }
  __syncthreads();

  // W0: pad rows + stage c0 (0-15) and c1 (16-47)
  if (tid < 68) { cbuf[3 * 68 + tid] = 0.0f; cbuf2[3 * 68 + tid] = 0.0f; }
  if (tid < 48) {
    int j = gl[tid];
    const float* p = xb + 3 * j;
    cbuf[0 * 68 + tid] = __fsub_rn(p[0], cx);
    cbuf[1 * 68 + tid] = __fsub_rn(p[1], cy);
    cbuf[2 * 68 + tid] = __fsub_rn(p[2], cz);
  }
  __syncthreads();

  // W1: L00  cbuf -> sB (stride 18)
  {
    float a[2][1]; ib<2, 1>(a, b00 + toc * 2);
    layer_acc<1, 2, 1, 68, 4>(wt + W00 + (toc * 2) * 4, cbuf, a, tn);
    store_relu<2, 1, 18>(sB + (toc * 2) * 18, a, tn);
  }
  __syncthreads();

  // W2: L01  sB -> sA (stride 18)
  {
    float a[2][1]; ib<2, 1>(a, b01 + toc * 2);
    layer_acc<8, 2, 1, 18, 32>(wt + W01 + (toc * 2) * 32, sB, a, tn);
    store_relu<2, 1, 18>(sA + (toc * 2) * 18, a, tn);
  }
  __syncthreads();

  // W3: L02 sA -> feat  ||  L10 cbuf+16 -> sB (stride 34)
  {
    float a[4][1]; ib<4, 1>(a, b02 + toc * 4);
    layer_acc<8, 4, 1, 18, 32>(wt + W02 + (toc * 4) * 32, sA, a, tn);
    float r[4] = {0.0f, 0.0f, 0.0f, 0.0f};
    rmax_upd<4, 1>(r, a);
    rmax_commit<4>(feat + toc * 4, r, tn);
    float a1[4][2]; ib<4, 2>(a1, b10 + toc * 4);
    layer_acc<1, 4, 2, 68, 4>(wt + W10 + (toc * 4) * 4, cbuf + 16, a1, tn);
    store_relu<4, 2, 34>(sB + (toc * 4) * 34, a1, tn);
  }
  __syncthreads();

  // W4: L11 sB -> sA (stride 34)  ||  stage c2 tile0 -> cbuf
  {
    float a[4][2]; ib<4, 2>(a, b11 + toc * 4);
    layer_acc<16, 4, 2, 34, 64>(wt + W11 + (toc * 4) * 64, sB, a, tn);
    store_relu<4, 2, 34>(sA + (toc * 4) * 34, a, tn);
    if (tid < 64) {
      int j = gl[48 + tid];
      const float* p = xb + 3 * j;
      cbuf[0 * 68 + tid] = __fsub_rn(p[0], cx);
      cbuf[1 * 68 + tid] = __fsub_rn(p[1], cy);
      cbuf[2 * 68 + tid] = __fsub_rn(p[2], cz);
    }
  }
  __syncthreads();

  // W5: L12 sA -> feat  ||  L20(t0) cbuf -> h1 (stride 64)
  {
    float a[8][2]; ib<8, 2>(a, b12 + toc * 8);
    layer_acc<16, 8, 2, 34, 64>(wt + W12 + (toc * 8) * 64, sA, a, tn);
    float r[8] = {0.0f, 0.0f, 0.0f, 0.0f, 0.0f, 0.0f, 0.0f, 0.0f};
    rmax_upd<8, 2>(r, a);
    rmax_commit<8>(feat + 64 + toc * 8, r, tn);
    float a2[4][4]; ib<4, 4>(a2, b20 + toc * 4);
    layer_acc<1, 4, 4, 68, 4>(wt + W20 + (toc * 4) * 4, cbuf, a2, tn);
    store_relu<4, 4, 64>(h1 + (toc * 4) * 64, a2, tn);
  }
  __syncthreads();

  // scale-2 wave scheme: lane = neighbor, wave owns an oc range.
  const int wq = __builtin_amdgcn_readfirstlane(wave);
  float rm2[32];
#pragma unroll
  for (int j = 0; j < 32; ++j) rm2[j] = 0.0f;

  // W6: L21(t0) h1 -> h2 (wave-uniform s_load weights) || stage c2t1 -> cbuf2
  {
    if (tid < 64) {
      int j = gl[112 + tid];
      const float* p = xb + 3 * j;
      cbuf2[0 * 68 + tid] = __fsub_rn(p[0], cx);
      cbuf2[1 * 68 + tid] = __fsub_rn(p[1], cy);
      cbuf2[2 * 68 + tid] = __fsub_rn(p[2], cz);
    }
    const float* wp = w21o + wq * 24;     // row k: wp[k*96 + j]
    const float* bp = b21 + wq * 24;
    float acc[24];
#pragma unroll
    for (int j = 0; j < 24; ++j) acc[j] = bp[j];
#pragma unroll 4
    for (int k = 0; k < 64; ++k) {
      float hv = h1[k * 64 + lane];
#pragma unroll
      for (int j = 0; j < 24; ++j) acc[j] = fmaf(hv, wp[k * 96 + j], acc[j]);
    }
#pragma unroll
    for (int j = 0; j < 24; ++j)
      h2[(wq * 24 + j) * 64 + lane] = fmaxf(acc[j], 0.0f);
  }
  __syncthreads();

  // W7: L20(t1) cbuf2 -> h1  ;  L22(t0) h2 -> rm2 (wave-uniform weights)
  {
    float a2[4][4]; ib<4, 4>(a2, b20 + toc * 4);
    layer_acc<1, 4, 4, 68, 4>(wt + W20 + (toc * 4) * 4, cbuf2, a2, tn);
    store_relu<4, 4, 64>(h1 + (toc * 4) * 64, a2, tn);
    const float* wp = w22o + wq * 32;     // row k: wp[k*128 + j]
    const float* bp = b22 + wq * 32;
    float acc[32];
#pragma unroll
    for (int j = 0; j < 32; ++j) acc[j] = bp[j];
#pragma unroll 2
    for (int k = 0; k < 96; ++k) {
      float hv = h2[k * 64 + lane];
#pragma unroll
      for (int j = 0; j < 32; ++j) acc[j] = fmaf(hv, wp[k * 128 + j], acc[j]);
    }
#pragma unroll
    for (int j = 0; j < 32; ++j) rm2[j] = fmaxf(rm2[j], fmaxf(acc[j], 0.0f));
  }
  __syncthreads();

  // W8: L21(t1) h1 -> h2
  {
    const float* wp = w21o + wq * 24;
    const float* bp = b21 + wq * 24;
    float acc[24];
#pragma unroll
    for (int j = 0; j < 24; ++j) acc[j] = bp[j];
#pragma unroll 4
    for (int k = 0; k < 64; ++k) {
      float hv = h1[k * 64 + lane];
#pragma unroll
      for (int j = 0; j < 24; ++j) acc[j] = fmaf(hv, wp[k * 96 + j], acc[j]);
    }
#pragma unroll
    for (int j = 0; j < 24; ++j)
      h2[(wq * 24 + j) * 64 + lane] = fmaxf(acc[j], 0.0f);
  }
  __syncthreads();

  // W9: L22(t1) h2 -> rm2 -> feat (DPP wave-max, lane 63 commits)
  {
    const float* wp = w22o + wq * 32;
    const float* bp = b22 + wq * 32;
    float acc[32];
#pragma unroll
    for (int j = 0; j < 32; ++j) acc[j] = bp[j];
#pragma unroll 2
    for (int k = 0; k < 96; ++k) {
      float hv = h2[k * 64 + lane];
#pragma unroll
      for (int j = 0; j < 32; ++j) acc[j] = fmaf(hv, wp[k * 128 + j], acc[j]);
    }
#pragma unroll
    for (int j = 0; j < 32; ++j) {
      float v = fmaxf(rm2[j], fmaxf(acc[j], 0.0f));
      v = wave_max(v);
      if (lane == 63) feat[192 + wq * 32 + j] = v;
    }
  }
  __syncthreads();

  // W10: final linear 320 -> 1
  if (tid < 64) {
    float sacc = 0.0f;
#pragma unroll
    for (int c = 0; c < 5; ++c) sacc += feat[tid + c * 64] * wf[tid + c * 64];
#pragma unroll
    for (int o = 32; o > 0; o >>= 1) sacc += __shfl_down(sacc, o);
    if (tid == 0) out[bs] = sacc + bf[0];
  }
}

extern "C" void kernel_launch(void* const* d_in, const int* in_sizes, int n_in,
                              void* d_out, int out_size, void* d_ws, size_t ws_size,
                              hipStream_t stream) {
  const float* pcd = (const float*)d_in[0];
  float* wsf = (float*)d_ws;
  float* new_xyz = wsf;                 // 12288 floats
  float* wt = wsf + 12288;              // 16000 floats
  int* ctrl = (int*)(wsf + 28288);      // [0]=claim, [8..15]=progress

  hipMemsetAsync(ctrl, 0, 64, stream);

  prep_kernel<<<(WT_TOTAL + 255) / 256, 256, 0, stream>>>(
      (const float*)d_in[1], (const float*)d_in[3], (const float*)d_in[5],
      (const float*)d_in[7], (const float*)d_in[9], (const float*)d_in[11],
      (const float*)d_in[13], wt);

  fused_kernel<<<BATCH * NSAMP + BATCH, 256, 0, stream>>>(
      pcd, new_xyz, ctrl, wt,
      (const float*)d_in[15], (const float*)d_in[17],
      (const float*)d_in[2],  (const float*)d_in[4],  (const float*)d_in[6],
      (const float*)d_in[8],  (const float*)d_in[10], (const float*)d_in[12],
      (const float*)d_in[14], (const float*)d_in[16], (const float*)d_in[18],
      (const float*)d_in[19], (const float*)d_in[20],
      (float*)d_out);
}